// Round 18
// baseline (917.854 us; speedup 1.0000x reference)
//
#include <hip/hip_runtime.h>
#include <math.h>
#include <stdint.h>

// Mamba2-lite mixer, round 18: r17 (best, 908us) + out-GEMM ported to the
// pipelined 256^2 kernel via an EP_F32 direct-store mode (f32 64B/wave
// segments, full-rate per r3). K-loop byte-identical to r17/r14 (proven
// schedule: per-phase lgkmcnt(0)+sched_barrier, 2 barriers/K-tile,
// fragment reuse Q0,Q1,Q3,Q2, vmcnt(2) stagger). 128^2 kernel removed.
// B=4, L=4096, Dm=1024, Di=2048, K=4.

#define BATCH 4
#define SEQ 4096
#define DMODEL 1024
#define DINNER 2048
#define CLS 32          // scan sub-chunk length

typedef __bf16 bf16_t;
typedef __bf16 bf16x8 __attribute__((ext_vector_type(8)));
typedef float f32x4 __attribute__((ext_vector_type(4)));
typedef unsigned short ushort_t;
typedef unsigned short u16x4 __attribute__((ext_vector_type(4)));

enum { EP_XZ = 0, EP_DBC = 1, EP_F32 = 2 };

__device__ __forceinline__ void gload_lds16(const void* g, void* l) {
    __builtin_amdgcn_global_load_lds(
        (const __attribute__((address_space(1))) void*)g,
        (__attribute__((address_space(3))) void*)l, 16, 0, 0);
}

__device__ __forceinline__ ushort_t f2bf(float f) {
    union { float f; uint32_t u; } c; c.f = f;
    uint32_t u = c.u;
    u += 0x7fffu + ((u >> 16) & 1u);          // RNE
    return (ushort_t)(u >> 16);
}
__device__ __forceinline__ float bf2f(ushort_t h) {
    union { uint32_t u; float f; } c; c.u = (uint32_t)h << 16;
    return c.f;
}
__device__ __forceinline__ float tanh_exact(float v) {
    v = fminf(fmaxf(v, -15.f), 15.f);
    float e = __expf(2.f * v);
    return (e - 1.f) / (e + 1.f);
}
__device__ __forceinline__ float tanh_poly(float v) {
    float v2 = v * v;
    float t = v * (1.f - v2 * (0.33333333f - 0.13333333f * v2));
    if (__builtin_expect(fabsf(v) > 0.25f, 0)) t = tanh_exact(v);
    return t;
}
__device__ __forceinline__ float softplus_poly(float v) {
    float v2 = v * v;
    float s = 0.69314718f + 0.5f * v + v2 * (0.125f - 0.0052083333f * v2);
    if (__builtin_expect(fabsf(v) > 0.25f, 0))
        s = fmaxf(v, 0.f) + __logf(1.f + __expf(-fabsf(v)));
    return s;
}

#define WAITV2 asm volatile("s_waitcnt vmcnt(2)" ::: "memory")
#define WAITV0 asm volatile("s_waitcnt vmcnt(0)" ::: "memory")
#define WAITL0 asm volatile("s_waitcnt lgkmcnt(0)" ::: "memory")

// ================= 256x256 8-wave GEMM, 2 barriers/K-tile (r14) ==========
__global__ __launch_bounds__(512) void gemm256_ep(
    const bf16_t* __restrict__ A, const bf16_t* __restrict__ W,
    const float* __restrict__ bias, float* __restrict__ Cf,
    ushort_t* __restrict__ T0, ushort_t* __restrict__ T1,
    ushort_t* __restrict__ T2, const float* __restrict__ alogp,
    int K, int Nout, int Lc, int a_bstride, int a_l0,
    int c_bstride, int c_l0, int mode)
{
    __shared__ __align__(16) char smem[131072];   // 2 x {A 32KB | B 32KB}
    const int tid = threadIdx.x;
    const int lane = tid & 63;
    const int wid = tid >> 6;          // 0..7
    const int wm2 = wid >> 2;          // 0..1 : 64-row band within quadrant
    const int wn2 = wid & 3;           // 0..3 : 32-col band within quadrant
    const int wz = blockIdx.z;
    const bf16_t* Wmat = W + (size_t)wz * Nout * K;
    ushort_t* Tz = (wz == 0) ? T0 : (wz == 1 ? T1 : T2);
    const int n0 = blockIdx.x * 256;
    const int m0 = blockIdx.y * 256;
    const int bb = m0 / Lc;
    const int lb = m0 - bb * Lc;
    const bf16_t* Abase = A + ((size_t)bb * a_bstride + a_l0 + lb) * K;
    const bf16_t* Wbase = Wmat + (size_t)n0 * K;

    int r_[2], c_[2], lofs_[2];
#pragma unroll
    for (int i = 0; i < 2; ++i) {
        int ofs = tid * 16 + i * 8192;
        int r = ofs >> 7;
        int c16 = (ofs >> 4) & 7;
        r_[i] = r;
        c_[i] = (c16 ^ (r & 7)) << 3;     // pre-swizzled global col (bf16)
        lofs_[i] = ofs;
    }

    const int nt = K / 64;

    f32x4 acc[4][4][2];                   // [quadrant][mi][ni]
#pragma unroll
    for (int q = 0; q < 4; ++q)
#pragma unroll
        for (int mi = 0; mi < 4; ++mi)
#pragma unroll
            for (int ni = 0; ni < 2; ++ni) acc[q][mi][ni] = f32x4{0.f, 0.f, 0.f, 0.f};

    // prologue: stage all 4 slots of tile 0 into buf0 (order A0,B0,B1,A1)
#pragma unroll
    for (int s = 0; s < 4; ++s) {
        const int isB_ = (s == 1 || s == 2);
        const int h_ = (s >= 2) ? 1 : 0;
        char* dst_ = smem + (isB_ ? 32768 : 0) + h_ * 16384;
        const bf16_t* g_ = isB_ ? Wbase : Abase;
        gload_lds16(g_ + (size_t)(h_ * 128 + r_[0]) * K + c_[0], dst_ + lofs_[0]);
        gload_lds16(g_ + (size_t)(h_ * 128 + r_[1]) * K + c_[1], dst_ + lofs_[1]);
    }

#define STAGE(S)                                                              \
    if (t + 1 < nt) {                                                         \
      char* base_ = smem + (((t + 1) & 1) ? 65536 : 0);                       \
      const int isB_ = ((S) == 1 || (S) == 2);                                \
      const int h_ = ((S) >= 2) ? 1 : 0;                                      \
      char* dst_ = base_ + (isB_ ? 32768 : 0) + h_ * 16384;                   \
      const bf16_t* g_ = isB_ ? Wbase : Abase;                                \
      const int k0_ = (t + 1) * 64;                                           \
      gload_lds16(g_ + (size_t)(h_ * 128 + r_[0]) * K + k0_ + c_[0],          \
                  dst_ + lofs_[0]);                                           \
      gload_lds16(g_ + (size_t)(h_ * 128 + r_[1]) * K + k0_ + c_[1],          \
                  dst_ + lofs_[1]);                                           \
    }

#define READ_A(dst, half)                                                     \
    _Pragma("unroll") for (int mi = 0; mi < 4; ++mi)                          \
    _Pragma("unroll") for (int ks = 0; ks < 2; ++ks) {                        \
      int row = (half) * 128 + wm2 * 64 + mi * 16 + (lane & 15);              \
      int cb = (ks * 64 + ((lane >> 4) << 4)) ^ ((row & 7) << 4);             \
      dst[mi][ks] = *(const bf16x8*)(bufb + row * 128 + cb);                  \
    }

#define READ_B(dst, half)                                                     \
    _Pragma("unroll") for (int ni = 0; ni < 2; ++ni)                          \
    _Pragma("unroll") for (int ks = 0; ks < 2; ++ks) {                        \
      int row = (half) * 128 + wn2 * 32 + ni * 16 + (lane & 15);              \
      int cb = (ks * 64 + ((lane >> 4) << 4)) ^ ((row & 7) << 4);             \
      dst[ni][ks] = *(const bf16x8*)(bufb + 32768 + row * 128 + cb);          \
    }

#define MMA(Q, AV, BV)                                                        \
    __builtin_amdgcn_s_setprio(1);                                            \
    _Pragma("unroll") for (int ks = 0; ks < 2; ++ks)                          \
    _Pragma("unroll") for (int mi = 0; mi < 4; ++mi)                          \
    _Pragma("unroll") for (int ni = 0; ni < 2; ++ni)                          \
      acc[(Q)][mi][ni] = __builtin_amdgcn_mfma_f32_16x16x32_bf16(             \
          AV[mi][ks], BV[ni][ks], acc[(Q)][mi][ni], 0, 0, 0);                 \
    __builtin_amdgcn_s_setprio(0);

    for (int t = 0; t < nt; ++t) {
        const char* bufb = smem + ((t & 1) ? 65536 : 0);
        bf16x8 av0[4][2], av1[4][2], bv0[2][2], bv1[2][2];
        // phase 0: stage A0(t+1); wait prior-tile stages; Q0 = av0 x bv0
        STAGE(0)
        if (t + 1 < nt) { WAITV2; } else { WAITV0; }
        __builtin_amdgcn_s_barrier();
        READ_A(av0, 0)
        READ_B(bv0, 0)
        WAITL0; __builtin_amdgcn_sched_barrier(0);
        MMA(0, av0, bv0)
        // phase 1 (no barrier): stage B0(t+1); Q1 = av0 x bv1
        STAGE(1)
        READ_B(bv1, 1)
        WAITL0; __builtin_amdgcn_sched_barrier(0);
        MMA(1, av0, bv1)
        // phase 2 (no barrier): stage B1(t+1); Q3 = av1 x bv1
        STAGE(2)
        READ_A(av1, 1)
        WAITL0; __builtin_amdgcn_sched_barrier(0);
        MMA(3, av1, bv1)
        // phase 3 (no reads): stage A1(t+1); Q2 = av1 x bv0
        STAGE(3)
        MMA(2, av1, bv0)
        __builtin_amdgcn_s_barrier();   // tile-end: protects WAR on buf t&1
    }
#undef STAGE
#undef READ_A
#undef READ_B
#undef MMA

    __syncthreads();

    const size_t rowbase = (size_t)bb * c_bstride + c_l0 + lb;
    if (mode == EP_F32) {
        // direct f32 stores (64B/wave segments, full-rate per r3)
#pragma unroll
        for (int q = 0; q < 4; ++q) {
#pragma unroll
            for (int ni = 0; ni < 2; ++ni) {
                const int col = (q & 1) * 128 + wn2 * 32 + ni * 16 + (lane & 15);
                const float bv = bias ? bias[n0 + col] : 0.f;
#pragma unroll
                for (int mi = 0; mi < 4; ++mi) {
#pragma unroll
                    for (int r4 = 0; r4 < 4; ++r4) {
                        const int row = (q >> 1) * 128 + wm2 * 64 + mi * 16 +
                                        ((lane >> 4) << 2) + r4;
                        Cf[(rowbase + row) * (size_t)Nout + n0 + col] =
                            acc[q][mi][ni][r4] + bv;
                    }
                }
            }
        }
        return;
    }

    // ---- bf16 epilogue: transform -> LDS (swizzled) -> 16B/lane stores ----
    ushort_t* sm = (ushort_t*)smem;
#pragma unroll
    for (int q = 0; q < 4; ++q) {
#pragma unroll
        for (int ni = 0; ni < 2; ++ni) {
            const int col = (q & 1) * 128 + wn2 * 32 + ni * 16 + (lane & 15);
            float bv = 0.f, Ae = 0.f;
            if (mode == EP_XZ) {
                bv = bias[wz * Nout + n0 + col];
            } else if (wz == 0) {   // EP_DBC decay slab
                bv = bias[n0 + col]; Ae = __expf(alogp[n0 + col]);
            }
#pragma unroll
            for (int mi = 0; mi < 4; ++mi) {
#pragma unroll
                for (int r4 = 0; r4 < 4; ++r4) {
                    const int row = (q >> 1) * 128 + wm2 * 64 + mi * 16 +
                                    ((lane >> 4) << 2) + r4;
                    float v = acc[q][mi][ni][r4] + bv;
                    ushort_t o;
                    if (mode == EP_XZ) {
                        o = (wz == 0) ? f2bf(v)
                                      : f2bf(1.f / (1.f + __expf(-v)));
                    } else {  // EP_DBC
                        if (wz == 0)
                            o = f2bf(__expf(-(softplus_poly(v) + 1e-4f) * Ae));
                        else
                            o = f2bf(tanh_poly(v));
                    }
                    const int sbyte = row * 512 + (((col * 2) ^ ((row & 7) << 4)));
                    *(ushort_t*)((char*)sm + sbyte) = o;
                }
            }
        }
    }
    __syncthreads();
#pragma unroll
    for (int it = 0; it < 16; ++it) {
        const int b0 = tid * 16 + it * 8192;
        const int row = b0 >> 9;
        const int inrow = b0 & 511;
        const int src = row * 512 + (inrow ^ ((row & 7) << 4));
        int4 vv = *(const int4*)((const char*)sm + src);
        *(int4*)(Tz + (rowbase + row) * (size_t)Nout + n0 + (inrow >> 1)) = vv;
    }
}

// ---------------- f32 -> bf16 conversion (one-time) ----------------------
__global__ __launch_bounds__(256) void cvt_bf16_k(
    const float4* __restrict__ in, ushort4* __restrict__ out, int n4)
{
    for (int i = blockIdx.x * 256 + threadIdx.x; i < n4; i += gridDim.x * 256) {
        float4 v = in[i];
        ushort4 o;
        o.x = f2bf(v.x); o.y = f2bf(v.y); o.z = f2bf(v.z); o.w = f2bf(v.w);
        out[i] = o;
    }
}

// ---------------- causal depthwise conv1d (k=4) + SiLU, bf16 ------------
__global__ __launch_bounds__(256) void conv_silu_bf(
    const ushort_t* __restrict__ xb, const ushort_t* __restrict__ tailb,
    const float* __restrict__ cw, const float* __restrict__ cb,
    ushort_t* __restrict__ ubf, int Lc, int l0, size_t total)
{
    for (size_t idx = (size_t)blockIdx.x * 256 + threadIdx.x; idx < total;
         idx += (size_t)gridDim.x * 256) {
        int e = (int)(idx % DINNER);
        size_t r = idx / DINNER;
        int lp = (int)(r % Lc);
        int b  = (int)(r / Lc);
        float4 w = *(const float4*)(cw + (size_t)e * 4);
        float s = cb[e];
        const ushort_t* xbase = xb + (size_t)b * Lc * DINNER + e;
        if (lp >= 3) {
            s += bf2f(xbase[(size_t)(lp - 3) * DINNER]) * w.x
               + bf2f(xbase[(size_t)(lp - 2) * DINNER]) * w.y
               + bf2f(xbase[(size_t)(lp - 1) * DINNER]) * w.z
               + bf2f(xbase[(size_t)lp * DINNER]) * w.w;
        } else {
            const float ws4[4] = {w.x, w.y, w.z, w.w};
            const ushort_t* tbase = tailb + (size_t)b * 3 * DINNER + e;
#pragma unroll
            for (int j = 0; j < 4; ++j) {
                int ls = lp - 3 + j;
                float v;
                if (ls >= 0)            v = bf2f(xbase[(size_t)ls * DINNER]);
                else if (l0 + ls >= 0)  v = bf2f(tbase[(size_t)(3 + ls) * DINNER]);
                else                    v = 0.f;
                s += v * ws4[j];
            }
        }
        ubf[idx] = f2bf(s / (1.f + __expf(-s)));
    }
}

__global__ __launch_bounds__(256) void tail_update_bf(
    const ushort_t* __restrict__ xb, ushort_t* __restrict__ tailb, int Lc)
{
    int idx = blockIdx.x * 256 + threadIdx.x;     // BATCH*3*DINNER
    if (idx >= BATCH * 3 * DINNER) return;
    int e = idx % DINNER;
    int j = (idx / DINNER) % 3;
    int b = idx / (3 * DINNER);
    tailb[idx] = xb[((size_t)b * Lc + Lc - 3 + j) * DINNER + e];
}

// ---------------- scan phase1: inc=(1-d)*bt*u on the fly, x4 ------------
__global__ __launch_bounds__(256) void scan1_v4(
    const ushort_t* __restrict__ dec, const ushort_t* __restrict__ bt,
    const ushort_t* __restrict__ ub,
    float* __restrict__ P, float* __restrict__ S, int Lc, int nsub)
{
    int t = blockIdx.x * 256 + threadIdx.x;    // BATCH*nsub*512 threads
    int e = (t & 511) << 2;
    int rest = t >> 9;
    int c = rest % nsub;
    int b = rest / nsub;
    size_t off = ((size_t)b * Lc + (size_t)c * CLS) * DINNER + e;
    float p[4] = {1.f, 1.f, 1.f, 1.f};
    float s[4] = {0.f, 0.f, 0.f, 0.f};
    for (int t0 = 0; t0 < CLS; ++t0) {
        size_t o = off + (size_t)t0 * DINNER;
        u16x4 d4 = *(const u16x4*)(dec + o);
        u16x4 b4 = *(const u16x4*)(bt + o);
        u16x4 u4 = *(const u16x4*)(ub + o);
#pragma unroll
        for (int j = 0; j < 4; ++j) {
            float d = bf2f(d4[j]);
            float inc = (1.f - d) * bf2f(b4[j]) * bf2f(u4[j]);
            s[j] = d * s[j] + inc;
            p[j] *= d;
        }
    }
    size_t po = ((size_t)b * nsub + c) * DINNER + e;
    *(float4*)(P + po) = float4{p[0], p[1], p[2], p[3]};
    *(float4*)(S + po) = float4{s[0], s[1], s[2], s[3]};
}

// ---------------- scan phase2: sequential combine over sub-chunks -------
__global__ __launch_bounds__(256) void scan_p2(
    float* __restrict__ P, float* __restrict__ S,
    float* __restrict__ carry, int nsub, int first)
{
    int idx = blockIdx.x * 256 + threadIdx.x;   // BATCH*DINNER
    int e = idx % DINNER;
    int b = idx / DINNER;
    float cv = first ? 0.f : carry[idx];
    for (int c = 0; c < nsub; ++c) {
        size_t o = ((size_t)b * nsub + c) * DINNER + e;
        float p = P[o], s = S[o];
        P[o] = cv;
        cv = p * cv + s;
    }
    carry[idx] = cv;
}

// ---------------- phase3 fused: replay + y=(ct*st+D*u)*sig -> bf16 ------
__global__ __launch_bounds__(256) void p3y_v4(
    const ushort_t* __restrict__ dec, ushort_t* __restrict__ bty,
    const ushort_t* __restrict__ ct, const ushort_t* __restrict__ ub,
    const ushort_t* __restrict__ sg, const float* __restrict__ Dp,
    const float* __restrict__ Pc, int Lc, int nsub)
{
    int t = blockIdx.x * 256 + threadIdx.x;    // BATCH*nsub*512 threads
    int e = (t & 511) << 2;
    int rest = t >> 9;
    int c = rest % nsub;
    int b = rest / nsub;
    size_t off = ((size_t)b * Lc + (size_t)c * CLS) * DINNER + e;
    size_t po = ((size_t)b * nsub + c) * DINNER + e;
    float4 stv = *(const float4*)(Pc + po);
    float4 Dv  = *(const float4*)(Dp + e);
    float st[4] = {stv.x, stv.y, stv.z, stv.w};
    float D4[4] = {Dv.x, Dv.y, Dv.z, Dv.w};
    for (int t0 = 0; t0 < CLS; ++t0) {
        size_t o = off + (size_t)t0 * DINNER;
        u16x4 d4 = *(const u16x4*)(dec + o);
        u16x4 b4 = *(const u16x4*)(bty + o);
        u16x4 c4 = *(const u16x4*)(ct + o);
        u16x4 u4 = *(const u16x4*)(ub + o);
        u16x4 g4 = *(const u16x4*)(sg + o);
        u16x4 y4;
#pragma unroll
        for (int j = 0; j < 4; ++j) {
            float d = bf2f(d4[j]);
            float u = bf2f(u4[j]);
            float inc = (1.f - d) * bf2f(b4[j]) * u;
            st[j] = d * st[j] + inc;
            float y = bf2f(c4[j]) * st[j] + D4[j] * u;
            y4[j] = f2bf(y * bf2f(g4[j]));
        }
        *(u16x4*)(bty + o) = y4;
    }
}

extern "C" void kernel_launch(void* const* d_in, const int* in_sizes, int n_in,
                              void* d_out, int out_size, void* d_ws, size_t ws_size,
                              hipStream_t stream)
{
    const float* x    = (const float*)d_in[0];
    const float* ipw  = (const float*)d_in[1];
    const float* ipb  = (const float*)d_in[2];
    const float* cw   = (const float*)d_in[3];
    const float* cb   = (const float*)d_in[4];
    const float* dtw  = (const float*)d_in[5];
    const float* dtb  = (const float*)d_in[6];
    const float* bw   = (const float*)d_in[7];
    const float* cwt  = (const float*)d_in[8];
    const float* alog = (const float*)d_in[9];
    const float* dpar = (const float*)d_in[10];
    const float* ow   = (const float*)d_in[11];
    const float* ob   = (const float*)d_in[12];
    float* out = (float*)d_out;

    const size_t XN   = (size_t)BATCH * SEQ * DMODEL;
    const size_t WIP  = (size_t)2 * DINNER * DMODEL;
    const size_t WSQ  = (size_t)DINNER * DINNER;
    const size_t WOUT = (size_t)DMODEL * DINNER;
    const size_t const_bytes = 2 * (XN + WIP + 3 * WSQ + WOUT);

    // ---- choose Lc (5 bf16 slots; min 256 for the 256-tile GEMM) ----
    const int cands[5] = {4096, 2048, 1024, 512, 256};
    int Lc = 256;
    for (int i = 0; i < 5; ++i) {
        size_t NBe = (size_t)BATCH * cands[i] * DINNER;
        size_t need = const_bytes
                    + 5 * NBe * 2
                    + (size_t)BATCH * 3 * DINNER * 2
                    + (size_t)BATCH * DINNER * 4
                    + 2 * (size_t)BATCH * (cands[i] / CLS) * DINNER * 4
                    + 1024;
        if (need <= ws_size) { Lc = cands[i]; break; }
    }
    const int nsub = Lc / CLS;
    const size_t NBe = (size_t)BATCH * Lc * DINNER;

    // ---- workspace layout ----
    char* p = (char*)d_ws;
    ushort_t* xbf   = (ushort_t*)p; p += XN * 2;
    ushort_t* ipwbf = (ushort_t*)p; p += WIP * 2;
    ushort_t* wcat  = (ushort_t*)p; p += 3 * WSQ * 2;   // [dtw; bw; cw]
    ushort_t* owbf  = (ushort_t*)p; p += WOUT * 2;
    ushort_t* S1 = (ushort_t*)p; p += NBe * 2;   // xb -> ct
    ushort_t* S2 = (ushort_t*)p; p += NBe * 2;   // u
    ushort_t* S3 = (ushort_t*)p; p += NBe * 2;   // decay
    ushort_t* S4 = (ushort_t*)p; p += NBe * 2;   // bt -> gated y
    ushort_t* S5 = (ushort_t*)p; p += NBe * 2;   // sigmoid(z)
    ushort_t* tailb = (ushort_t*)p; p += (size_t)BATCH * 3 * DINNER * 2;
    float* carry = (float*)p; p += (size_t)BATCH * DINNER * 4;
    float* Pb    = (float*)p; p += (size_t)BATCH * nsub * DINNER * 4;
    float* Sb    = (float*)p;

    const dim3 blk(256);
    const dim3 blk512(512);
    const int M = BATCH * Lc;
    const dim3 gXZ(DINNER / 256, M / 256, 2);
    const dim3 gDBC(DINNER / 256, M / 256, 3);
    const dim3 gOut(DMODEL / 256, M / 256, 1);
    const int pwBlocks = (int)(((NBe + 255) / 256 < 4096) ? (NBe + 255) / 256 : 4096);
    const int scanBlocks = BATCH * nsub * 2;     // x4 vectorized, 512 thr/(b,c)

    auto cvt = [&](const float* in, ushort_t* outp, size_t n) {
        int n4 = (int)(n / 4);
        int g = n4 / 256 < 2048 ? (n4 + 255) / 256 : 2048;
        cvt_bf16_k<<<g, blk, 0, stream>>>((const float4*)in, (ushort4*)outp, n4);
    };
    cvt(x, xbf, XN);
    cvt(ipw, ipwbf, WIP);
    cvt(dtw, wcat, WSQ);
    cvt(bw, wcat + WSQ, WSQ);
    cvt(cwt, wcat + 2 * WSQ, WSQ);
    cvt(ow, owbf, WOUT);

    const int nchunks = SEQ / Lc;
    for (int c = 0; c < nchunks; ++c) {
        const int l0 = c * Lc;
        // 1. z=2: xb(S1) | sig(z)(S5) = epilogues of x @ ipw^T  (A fetched once)
        gemm256_ep<<<gXZ, blk512, 0, stream>>>(
            (const bf16_t*)xbf, (const bf16_t*)ipwbf, ipb, nullptr,
            S1, S5, nullptr, nullptr,
            DMODEL, DINNER, Lc, SEQ, l0, Lc, 0, EP_XZ);
        // 2. u = silu(conv(xb))
        conv_silu_bf<<<pwBlocks, blk, 0, stream>>>(S1, tailb, cw, cb, S2, Lc, l0, NBe);
        if (nchunks > 1)
            tail_update_bf<<<BATCH * 3 * DINNER / 256, blk, 0, stream>>>(S1, tailb, Lc);
        // 3. z=3: decay(S3) | bt(S4) | ct(S1) from u @ [dtw;bw;cw]^T
        gemm256_ep<<<gDBC, blk512, 0, stream>>>(
            (const bf16_t*)S2, (const bf16_t*)wcat, dtb, nullptr,
            S3, S4, S1, alog,
            DINNER, DINNER, Lc, Lc, 0, Lc, 0, EP_DBC);
        // 4-5. scan partials + combine (inc computed on the fly)
        scan1_v4<<<scanBlocks, blk, 0, stream>>>(S3, S4, S2, Pb, Sb, Lc, nsub);
        scan_p2<<<BATCH * DINNER / 256, blk, 0, stream>>>(Pb, Sb, carry, nsub, c == 0);
        // 6. replay + y = (ct*st + D*u)*sig -> gated ybf (in place over S4)
        p3y_v4<<<scanBlocks, blk, 0, stream>>>(S3, S4, S1, S2, S5, dpar, Pb, Lc, nsub);
        // 7. out = y @ ow^T + ob  (f32, pipelined 256^2)
        gemm256_ep<<<gOut, blk512, 0, stream>>>(
            (const bf16_t*)S4, (const bf16_t*)owbf, ob, out,
            nullptr, nullptr, nullptr, nullptr,
            DINNER, DMODEL, Lc, Lc, 0, SEQ, l0, EP_F32);
    }
}

// Round 19
// 906.710 us; speedup vs baseline: 1.0123x; 1.0123x over previous
//
#include <hip/hip_runtime.h>
#include <math.h>
#include <stdint.h>

// Mamba2-lite mixer, round 19 == round 17 (best measured: 908us).
// r18's out-GEMM-on-256^2 reverted: its grid was 4x32=128 blocks for
// 256 CUs (half chip idle, G11 violation); the 128^2 out kernel (512
// blocks, 2/CU) is the right shape for N=1024.
// Structure: pipelined 256^2 GEMM (r14 schedule: per-phase lgkmcnt(0)+
// sched_barrier, 2 barriers/K-tile, fragment reuse Q0,Q1,Q3,Q2, vmcnt(2)
// stagger, XOR-swizzled LDS both-sides, LDS-staged bf16 epilogue stores),
// merged XZ (z=2) and DBC (z=3) launches, poly epilogues, gated p3y,
// chunked scan with cross-chunk carry. Lc=2048 (ws ~256MB), 2 chunks.
// B=4, L=4096, Dm=1024, Di=2048, K=4.

#define BATCH 4
#define SEQ 4096
#define DMODEL 1024
#define DINNER 2048
#define CLS 32          // scan sub-chunk length

typedef __bf16 bf16_t;
typedef __bf16 bf16x8 __attribute__((ext_vector_type(8)));
typedef float f32x4 __attribute__((ext_vector_type(4)));
typedef unsigned short ushort_t;
typedef unsigned short u16x4 __attribute__((ext_vector_type(4)));

enum { EP_XZ = 0, EP_DBC = 1 };

__device__ __forceinline__ void gload_lds16(const void* g, void* l) {
    __builtin_amdgcn_global_load_lds(
        (const __attribute__((address_space(1))) void*)g,
        (__attribute__((address_space(3))) void*)l, 16, 0, 0);
}

__device__ __forceinline__ ushort_t f2bf(float f) {
    union { float f; uint32_t u; } c; c.f = f;
    uint32_t u = c.u;
    u += 0x7fffu + ((u >> 16) & 1u);          // RNE
    return (ushort_t)(u >> 16);
}
__device__ __forceinline__ float bf2f(ushort_t h) {
    union { uint32_t u; float f; } c; c.u = (uint32_t)h << 16;
    return c.f;
}
__device__ __forceinline__ float tanh_exact(float v) {
    v = fminf(fmaxf(v, -15.f), 15.f);
    float e = __expf(2.f * v);
    return (e - 1.f) / (e + 1.f);
}
__device__ __forceinline__ float tanh_poly(float v) {
    float v2 = v * v;
    float t = v * (1.f - v2 * (0.33333333f - 0.13333333f * v2));
    if (__builtin_expect(fabsf(v) > 0.25f, 0)) t = tanh_exact(v);
    return t;
}
__device__ __forceinline__ float softplus_poly(float v) {
    float v2 = v * v;
    float s = 0.69314718f + 0.5f * v + v2 * (0.125f - 0.0052083333f * v2);
    if (__builtin_expect(fabsf(v) > 0.25f, 0))
        s = fmaxf(v, 0.f) + __logf(1.f + __expf(-fabsf(v)));
    return s;
}

#define WAITV2 asm volatile("s_waitcnt vmcnt(2)" ::: "memory")
#define WAITV0 asm volatile("s_waitcnt vmcnt(0)" ::: "memory")
#define WAITL0 asm volatile("s_waitcnt lgkmcnt(0)" ::: "memory")

// ================= 256x256 8-wave GEMM, 2 barriers/K-tile (r14) ==========
__global__ __launch_bounds__(512) void gemm256_ep(
    const bf16_t* __restrict__ A, const bf16_t* __restrict__ W,
    const float* __restrict__ bias,
    ushort_t* __restrict__ T0, ushort_t* __restrict__ T1,
    ushort_t* __restrict__ T2, const float* __restrict__ alogp,
    int K, int Nout, int Lc, int a_bstride, int a_l0,
    int c_bstride, int c_l0, int mode)
{
    __shared__ __align__(16) char smem[131072];   // 2 x {A 32KB | B 32KB}
    const int tid = threadIdx.x;
    const int lane = tid & 63;
    const int wid = tid >> 6;          // 0..7
    const int wm2 = wid >> 2;          // 0..1 : 64-row band within quadrant
    const int wn2 = wid & 3;           // 0..3 : 32-col band within quadrant
    const int wz = blockIdx.z;
    const bf16_t* Wmat = W + (size_t)wz * Nout * K;
    ushort_t* Tz = (wz == 0) ? T0 : (wz == 1 ? T1 : T2);
    const int n0 = blockIdx.x * 256;
    const int m0 = blockIdx.y * 256;
    const int bb = m0 / Lc;
    const int lb = m0 - bb * Lc;
    const bf16_t* Abase = A + ((size_t)bb * a_bstride + a_l0 + lb) * K;
    const bf16_t* Wbase = Wmat + (size_t)n0 * K;

    int r_[2], c_[2], lofs_[2];
#pragma unroll
    for (int i = 0; i < 2; ++i) {
        int ofs = tid * 16 + i * 8192;
        int r = ofs >> 7;
        int c16 = (ofs >> 4) & 7;
        r_[i] = r;
        c_[i] = (c16 ^ (r & 7)) << 3;     // pre-swizzled global col (bf16)
        lofs_[i] = ofs;
    }

    const int nt = K / 64;

    f32x4 acc[4][4][2];                   // [quadrant][mi][ni]
#pragma unroll
    for (int q = 0; q < 4; ++q)
#pragma unroll
        for (int mi = 0; mi < 4; ++mi)
#pragma unroll
            for (int ni = 0; ni < 2; ++ni) acc[q][mi][ni] = f32x4{0.f, 0.f, 0.f, 0.f};

    // prologue: stage all 4 slots of tile 0 into buf0 (order A0,B0,B1,A1)
#pragma unroll
    for (int s = 0; s < 4; ++s) {
        const int isB_ = (s == 1 || s == 2);
        const int h_ = (s >= 2) ? 1 : 0;
        char* dst_ = smem + (isB_ ? 32768 : 0) + h_ * 16384;
        const bf16_t* g_ = isB_ ? Wbase : Abase;
        gload_lds16(g_ + (size_t)(h_ * 128 + r_[0]) * K + c_[0], dst_ + lofs_[0]);
        gload_lds16(g_ + (size_t)(h_ * 128 + r_[1]) * K + c_[1], dst_ + lofs_[1]);
    }

#define STAGE(S)                                                              \
    if (t + 1 < nt) {                                                         \
      char* base_ = smem + (((t + 1) & 1) ? 65536 : 0);                       \
      const int isB_ = ((S) == 1 || (S) == 2);                                \
      const int h_ = ((S) >= 2) ? 1 : 0;                                      \
      char* dst_ = base_ + (isB_ ? 32768 : 0) + h_ * 16384;                   \
      const bf16_t* g_ = isB_ ? Wbase : Abase;                                \
      const int k0_ = (t + 1) * 64;                                           \
      gload_lds16(g_ + (size_t)(h_ * 128 + r_[0]) * K + k0_ + c_[0],          \
                  dst_ + lofs_[0]);                                           \
      gload_lds16(g_ + (size_t)(h_ * 128 + r_[1]) * K + k0_ + c_[1],          \
                  dst_ + lofs_[1]);                                           \
    }

#define READ_A(dst, half)                                                     \
    _Pragma("unroll") for (int mi = 0; mi < 4; ++mi)                          \
    _Pragma("unroll") for (int ks = 0; ks < 2; ++ks) {                        \
      int row = (half) * 128 + wm2 * 64 + mi * 16 + (lane & 15);              \
      int cb = (ks * 64 + ((lane >> 4) << 4)) ^ ((row & 7) << 4);             \
      dst[mi][ks] = *(const bf16x8*)(bufb + row * 128 + cb);                  \
    }

#define READ_B(dst, half)                                                     \
    _Pragma("unroll") for (int ni = 0; ni < 2; ++ni)                          \
    _Pragma("unroll") for (int ks = 0; ks < 2; ++ks) {                        \
      int row = (half) * 128 + wn2 * 32 + ni * 16 + (lane & 15);              \
      int cb = (ks * 64 + ((lane >> 4) << 4)) ^ ((row & 7) << 4);             \
      dst[ni][ks] = *(const bf16x8*)(bufb + 32768 + row * 128 + cb);          \
    }

#define MMA(Q, AV, BV)                                                        \
    __builtin_amdgcn_s_setprio(1);                                            \
    _Pragma("unroll") for (int ks = 0; ks < 2; ++ks)                          \
    _Pragma("unroll") for (int mi = 0; mi < 4; ++mi)                          \
    _Pragma("unroll") for (int ni = 0; ni < 2; ++ni)                          \
      acc[(Q)][mi][ni] = __builtin_amdgcn_mfma_f32_16x16x32_bf16(             \
          AV[mi][ks], BV[ni][ks], acc[(Q)][mi][ni], 0, 0, 0);                 \
    __builtin_amdgcn_s_setprio(0);

    for (int t = 0; t < nt; ++t) {
        const char* bufb = smem + ((t & 1) ? 65536 : 0);
        bf16x8 av0[4][2], av1[4][2], bv0[2][2], bv1[2][2];
        // phase 0: stage A0(t+1); wait prior-tile stages; Q0 = av0 x bv0
        STAGE(0)
        if (t + 1 < nt) { WAITV2; } else { WAITV0; }
        __builtin_amdgcn_s_barrier();
        READ_A(av0, 0)
        READ_B(bv0, 0)
        WAITL0; __builtin_amdgcn_sched_barrier(0);
        MMA(0, av0, bv0)
        // phase 1 (no barrier): stage B0(t+1); Q1 = av0 x bv1
        STAGE(1)
        READ_B(bv1, 1)
        WAITL0; __builtin_amdgcn_sched_barrier(0);
        MMA(1, av0, bv1)
        // phase 2 (no barrier): stage B1(t+1); Q3 = av1 x bv1
        STAGE(2)
        READ_A(av1, 1)
        WAITL0; __builtin_amdgcn_sched_barrier(0);
        MMA(3, av1, bv1)
        // phase 3 (no reads): stage A1(t+1); Q2 = av1 x bv0
        STAGE(3)
        MMA(2, av1, bv0)
        __builtin_amdgcn_s_barrier();   // tile-end: protects WAR on buf t&1
    }
#undef STAGE
#undef READ_A
#undef READ_B
#undef MMA

    __syncthreads();

    // ---- epilogue: transform -> LDS C-tile (swizzled) -> 16B/lane stores ----
    const size_t rowbase = (size_t)bb * c_bstride + c_l0 + lb;
    ushort_t* sm = (ushort_t*)smem;
#pragma unroll
    for (int q = 0; q < 4; ++q) {
#pragma unroll
        for (int ni = 0; ni < 2; ++ni) {
            const int col = (q & 1) * 128 + wn2 * 32 + ni * 16 + (lane & 15);
            float bv = 0.f, Ae = 0.f;
            if (mode == EP_XZ) {
                bv = bias[wz * Nout + n0 + col];
            } else if (wz == 0) {   // EP_DBC decay slab
                bv = bias[n0 + col]; Ae = __expf(alogp[n0 + col]);
            }
#pragma unroll
            for (int mi = 0; mi < 4; ++mi) {
#pragma unroll
                for (int r4 = 0; r4 < 4; ++r4) {
                    const int row = (q >> 1) * 128 + wm2 * 64 + mi * 16 +
                                    ((lane >> 4) << 2) + r4;
                    float v = acc[q][mi][ni][r4] + bv;
                    ushort_t o;
                    if (mode == EP_XZ) {
                        o = (wz == 0) ? f2bf(v)
                                      : f2bf(1.f / (1.f + __expf(-v)));
                    } else {  // EP_DBC
                        if (wz == 0)
                            o = f2bf(__expf(-(softplus_poly(v) + 1e-4f) * Ae));
                        else
                            o = f2bf(tanh_poly(v));
                    }
                    const int sbyte = row * 512 + (((col * 2) ^ ((row & 7) << 4)));
                    *(ushort_t*)((char*)sm + sbyte) = o;
                }
            }
        }
    }
    __syncthreads();
#pragma unroll
    for (int it = 0; it < 16; ++it) {
        const int b0 = tid * 16 + it * 8192;
        const int row = b0 >> 9;
        const int inrow = b0 & 511;
        const int src = row * 512 + (inrow ^ ((row & 7) << 4));
        int4 vv = *(const int4*)((const char*)sm + src);
        *(int4*)(Tz + (rowbase + row) * (size_t)Nout + n0 + (inrow >> 1)) = vv;
    }
}

// ================= 128x128 GEMM (f32 out; proven) ========================
#define GBK 64

__global__ __launch_bounds__(256) void gemm_f32out(
    const bf16_t* __restrict__ A, const bf16_t* __restrict__ W,
    const float* __restrict__ bias, float* __restrict__ Cf,
    int K, int Nout, int Lc, int a_bstride, int a_l0,
    int c_bstride, int c_l0)
{
    __shared__ __align__(16) bf16_t smem[128 * 128];
    bf16_t* sA = smem;
    bf16_t* sB = smem + 128 * GBK;
    const int tid = threadIdx.x;
    const int lane = tid & 63;
    const int wid = tid >> 6;
    const int wm = wid >> 1, wn = wid & 1;
    const int n0 = blockIdx.x * 128;
    const int m0 = blockIdx.y * 128;
    const int bb = m0 / Lc;
    const int lb = m0 - bb * Lc;
    const bf16_t* Abase = A + ((size_t)bb * a_bstride + a_l0 + lb) * K;
    const bf16_t* Wbase = W + (size_t)n0 * K;

    int st_row[4], st_sc[4], st_ofs[4];
#pragma unroll
    for (int i = 0; i < 4; ++i) {
        int ofs = tid * 16 + i * 4096;
        int r = ofs >> 7;
        int c16 = (ofs >> 4) & 7;
        st_ofs[i] = ofs;
        st_row[i] = r;
        st_sc[i] = (c16 ^ (r & 7)) << 3;
    }

    f32x4 acc[4][4];
#pragma unroll
    for (int i = 0; i < 4; ++i)
#pragma unroll
        for (int j = 0; j < 4; ++j) acc[i][j] = f32x4{0.f, 0.f, 0.f, 0.f};

    for (int k0 = 0; k0 < K; k0 += GBK) {
#pragma unroll
        for (int i = 0; i < 4; ++i) {
            gload_lds16(Abase + (size_t)st_row[i] * K + k0 + st_sc[i],
                        (char*)sA + st_ofs[i]);
            gload_lds16(Wbase + (size_t)st_row[i] * K + k0 + st_sc[i],
                        (char*)sB + st_ofs[i]);
        }
        __syncthreads();
#pragma unroll
        for (int ks = 0; ks < 2; ++ks) {
            bf16x8 av[4], bv[4];
#pragma unroll
            for (int mi = 0; mi < 4; ++mi) {
                int row = wm * 64 + mi * 16 + (lane & 15);
                int cb = (ks * 64 + ((lane >> 4) << 4)) ^ ((row & 7) << 4);
                av[mi] = *(const bf16x8*)((const char*)sA + row * 128 + cb);
            }
#pragma unroll
            for (int ni = 0; ni < 4; ++ni) {
                int row = wn * 64 + ni * 16 + (lane & 15);
                int cb = (ks * 64 + ((lane >> 4) << 4)) ^ ((row & 7) << 4);
                bv[ni] = *(const bf16x8*)((const char*)sB + row * 128 + cb);
            }
#pragma unroll
            for (int mi = 0; mi < 4; ++mi)
#pragma unroll
                for (int ni = 0; ni < 4; ++ni)
                    acc[mi][ni] = __builtin_amdgcn_mfma_f32_16x16x32_bf16(
                        av[mi], bv[ni], acc[mi][ni], 0, 0, 0);
        }
        __syncthreads();
    }

    const size_t rowbase = (size_t)bb * c_bstride + c_l0 + lb;
#pragma unroll
    for (int ni = 0; ni < 4; ++ni) {
        const int coll = wn * 64 + ni * 16 + (lane & 15);
        const float bv = bias ? bias[n0 + coll] : 0.f;
#pragma unroll
        for (int mi = 0; mi < 4; ++mi) {
#pragma unroll
            for (int r4 = 0; r4 < 4; ++r4) {
                const int rowl = wm * 64 + mi * 16 + ((lane >> 4) << 2) + r4;
                Cf[(rowbase + rowl) * (size_t)Nout + n0 + coll] =
                    acc[mi][ni][r4] + bv;
            }
        }
    }
}

// ---------------- f32 -> bf16 conversion (one-time) ----------------------
__global__ __launch_bounds__(256) void cvt_bf16_k(
    const float4* __restrict__ in, ushort4* __restrict__ out, int n4)
{
    for (int i = blockIdx.x * 256 + threadIdx.x; i < n4; i += gridDim.x * 256) {
        float4 v = in[i];
        ushort4 o;
        o.x = f2bf(v.x); o.y = f2bf(v.y); o.z = f2bf(v.z); o.w = f2bf(v.w);
        out[i] = o;
    }
}

// ---------------- causal depthwise conv1d (k=4) + SiLU, bf16 ------------
__global__ __launch_bounds__(256) void conv_silu_bf(
    const ushort_t* __restrict__ xb, const ushort_t* __restrict__ tailb,
    const float* __restrict__ cw, const float* __restrict__ cb,
    ushort_t* __restrict__ ubf, int Lc, int l0, size_t total)
{
    for (size_t idx = (size_t)blockIdx.x * 256 + threadIdx.x; idx < total;
         idx += (size_t)gridDim.x * 256) {
        int e = (int)(idx % DINNER);
        size_t r = idx / DINNER;
        int lp = (int)(r % Lc);
        int b  = (int)(r / Lc);
        float4 w = *(const float4*)(cw + (size_t)e * 4);
        float s = cb[e];
        const ushort_t* xbase = xb + (size_t)b * Lc * DINNER + e;
        if (lp >= 3) {
            s += bf2f(xbase[(size_t)(lp - 3) * DINNER]) * w.x
               + bf2f(xbase[(size_t)(lp - 2) * DINNER]) * w.y
               + bf2f(xbase[(size_t)(lp - 1) * DINNER]) * w.z
               + bf2f(xbase[(size_t)lp * DINNER]) * w.w;
        } else {
            const float ws4[4] = {w.x, w.y, w.z, w.w};
            const ushort_t* tbase = tailb + (size_t)b * 3 * DINNER + e;
#pragma unroll
            for (int j = 0; j < 4; ++j) {
                int ls = lp - 3 + j;
                float v;
                if (ls >= 0)            v = bf2f(xbase[(size_t)ls * DINNER]);
                else if (l0 + ls >= 0)  v = bf2f(tbase[(size_t)(3 + ls) * DINNER]);
                else                    v = 0.f;
                s += v * ws4[j];
            }
        }
        ubf[idx] = f2bf(s / (1.f + __expf(-s)));
    }
}

__global__ __launch_bounds__(256) void tail_update_bf(
    const ushort_t* __restrict__ xb, ushort_t* __restrict__ tailb, int Lc)
{
    int idx = blockIdx.x * 256 + threadIdx.x;     // BATCH*3*DINNER
    if (idx >= BATCH * 3 * DINNER) return;
    int e = idx % DINNER;
    int j = (idx / DINNER) % 3;
    int b = idx / (3 * DINNER);
    tailb[idx] = xb[((size_t)b * Lc + Lc - 3 + j) * DINNER + e];
}

// ---------------- scan phase1: inc=(1-d)*bt*u on the fly, x4 ------------
__global__ __launch_bounds__(256) void scan1_v4(
    const ushort_t* __restrict__ dec, const ushort_t* __restrict__ bt,
    const ushort_t* __restrict__ ub,
    float* __restrict__ P, float* __restrict__ S, int Lc, int nsub)
{
    int t = blockIdx.x * 256 + threadIdx.x;    // BATCH*nsub*512 threads
    int e = (t & 511) << 2;
    int rest = t >> 9;
    int c = rest % nsub;
    int b = rest / nsub;
    size_t off = ((size_t)b * Lc + (size_t)c * CLS) * DINNER + e;
    float p[4] = {1.f, 1.f, 1.f, 1.f};
    float s[4] = {0.f, 0.f, 0.f, 0.f};
    for (int t0 = 0; t0 < CLS; ++t0) {
        size_t o = off + (size_t)t0 * DINNER;
        u16x4 d4 = *(const u16x4*)(dec + o);
        u16x4 b4 = *(const u16x4*)(bt + o);
        u16x4 u4 = *(const u16x4*)(ub + o);
#pragma unroll
        for (int j = 0; j < 4; ++j) {
            float d = bf2f(d4[j]);
            float inc = (1.f - d) * bf2f(b4[j]) * bf2f(u4[j]);
            s[j] = d * s[j] + inc;
            p[j] *= d;
        }
    }
    size_t po = ((size_t)b * nsub + c) * DINNER + e;
    *(float4*)(P + po) = float4{p[0], p[1], p[2], p[3]};
    *(float4*)(S + po) = float4{s[0], s[1], s[2], s[3]};
}

// ---------------- scan phase2: sequential combine over sub-chunks -------
__global__ __launch_bounds__(256) void scan_p2(
    float* __restrict__ P, float* __restrict__ S,
    float* __restrict__ carry, int nsub, int first)
{
    int idx = blockIdx.x * 256 + threadIdx.x;   // BATCH*DINNER
    int e = idx % DINNER;
    int b = idx / DINNER;
    float cv = first ? 0.f : carry[idx];
    for (int c = 0; c < nsub; ++c) {
        size_t o = ((size_t)b * nsub + c) * DINNER + e;
        float p = P[o], s = S[o];
        P[o] = cv;
        cv = p * cv + s;
    }
    carry[idx] = cv;
}

// ---------------- phase3 fused: replay + y=(ct*st+D*u)*sig -> bf16 ------
// bt buffer is overwritten in place with gated ybf.
__global__ __launch_bounds__(256) void p3y_v4(
    const ushort_t* __restrict__ dec, ushort_t* __restrict__ bty,
    const ushort_t* __restrict__ ct, const ushort_t* __restrict__ ub,
    const ushort_t* __restrict__ sg, const float* __restrict__ Dp,
    const float* __restrict__ Pc, int Lc, int nsub)
{
    int t = blockIdx.x * 256 + threadIdx.x;    // BATCH*nsub*512 threads
    int e = (t & 511) << 2;
    int rest = t >> 9;
    int c = rest % nsub;
    int b = rest / nsub;
    size_t off = ((size_t)b * Lc + (size_t)c * CLS) * DINNER + e;
    size_t po = ((size_t)b * nsub + c) * DINNER + e;
    float4 stv = *(const float4*)(Pc + po);
    float4 Dv  = *(const float4*)(Dp + e);
    float st[4] = {stv.x, stv.y, stv.z, stv.w};
    float D4[4] = {Dv.x, Dv.y, Dv.z, Dv.w};
    for (int t0 = 0; t0 < CLS; ++t0) {
        size_t o = off + (size_t)t0 * DINNER;
        u16x4 d4 = *(const u16x4*)(dec + o);
        u16x4 b4 = *(const u16x4*)(bty + o);
        u16x4 c4 = *(const u16x4*)(ct + o);
        u16x4 u4 = *(const u16x4*)(ub + o);
        u16x4 g4 = *(const u16x4*)(sg + o);
        u16x4 y4;
#pragma unroll
        for (int j = 0; j < 4; ++j) {
            float d = bf2f(d4[j]);
            float u = bf2f(u4[j]);
            float inc = (1.f - d) * bf2f(b4[j]) * u;
            st[j] = d * st[j] + inc;
            float y = bf2f(c4[j]) * st[j] + D4[j] * u;
            y4[j] = f2bf(y * bf2f(g4[j]));
        }
        *(u16x4*)(bty + o) = y4;
    }
}

extern "C" void kernel_launch(void* const* d_in, const int* in_sizes, int n_in,
                              void* d_out, int out_size, void* d_ws, size_t ws_size,
                              hipStream_t stream)
{
    const float* x    = (const float*)d_in[0];
    const float* ipw  = (const float*)d_in[1];
    const float* ipb  = (const float*)d_in[2];
    const float* cw   = (const float*)d_in[3];
    const float* cb   = (const float*)d_in[4];
    const float* dtw  = (const float*)d_in[5];
    const float* dtb  = (const float*)d_in[6];
    const float* bw   = (const float*)d_in[7];
    const float* cwt  = (const float*)d_in[8];
    const float* alog = (const float*)d_in[9];
    const float* dpar = (const float*)d_in[10];
    const float* ow   = (const float*)d_in[11];
    const float* ob   = (const float*)d_in[12];
    float* out = (float*)d_out;

    const size_t XN   = (size_t)BATCH * SEQ * DMODEL;
    const size_t WIP  = (size_t)2 * DINNER * DMODEL;
    const size_t WSQ  = (size_t)DINNER * DINNER;
    const size_t WOUT = (size_t)DMODEL * DINNER;
    const size_t const_bytes = 2 * (XN + WIP + 3 * WSQ + WOUT);

    // ---- choose Lc (5 bf16 slots; min 256 for the 256-tile GEMM) ----
    const int cands[5] = {4096, 2048, 1024, 512, 256};
    int Lc = 256;
    for (int i = 0; i < 5; ++i) {
        size_t NBe = (size_t)BATCH * cands[i] * DINNER;
        size_t need = const_bytes
                    + 5 * NBe * 2
                    + (size_t)BATCH * 3 * DINNER * 2
                    + (size_t)BATCH * DINNER * 4
                    + 2 * (size_t)BATCH * (cands[i] / CLS) * DINNER * 4
                    + 1024;
        if (need <= ws_size) { Lc = cands[i]; break; }
    }
    const int nsub = Lc / CLS;
    const size_t NBe = (size_t)BATCH * Lc * DINNER;

    // ---- workspace layout ----
    char* p = (char*)d_ws;
    ushort_t* xbf   = (ushort_t*)p; p += XN * 2;
    ushort_t* ipwbf = (ushort_t*)p; p += WIP * 2;
    ushort_t* wcat  = (ushort_t*)p; p += 3 * WSQ * 2;   // [dtw; bw; cw]
    ushort_t* owbf  = (ushort_t*)p; p += WOUT * 2;
    ushort_t* S1 = (ushort_t*)p; p += NBe * 2;   // xb -> ct
    ushort_t* S2 = (ushort_t*)p; p += NBe * 2;   // u
    ushort_t* S3 = (ushort_t*)p; p += NBe * 2;   // decay
    ushort_t* S4 = (ushort_t*)p; p += NBe * 2;   // bt -> gated y
    ushort_t* S5 = (ushort_t*)p; p += NBe * 2;   // sigmoid(z)
    ushort_t* tailb = (ushort_t*)p; p += (size_t)BATCH * 3 * DINNER * 2;
    float* carry = (float*)p; p += (size_t)BATCH * DINNER * 4;
    float* Pb    = (float*)p; p += (size_t)BATCH * nsub * DINNER * 4;
    float* Sb    = (float*)p;

    const dim3 blk(256);
    const dim3 blk512(512);
    const int M = BATCH * Lc;
    const dim3 gXZ(DINNER / 256, M / 256, 2);
    const dim3 gDBC(DINNER / 256, M / 256, 3);
    const dim3 gOut(DMODEL / 128, M / 128, 1);
    const int pwBlocks = (int)(((NBe + 255) / 256 < 4096) ? (NBe + 255) / 256 : 4096);
    const int scanBlocks = BATCH * nsub * 2;     // x4 vectorized, 512 thr/(b,c)

    auto cvt = [&](const float* in, ushort_t* outp, size_t n) {
        int n4 = (int)(n / 4);
        int g = n4 / 256 < 2048 ? (n4 + 255) / 256 : 2048;
        cvt_bf16_k<<<g, blk, 0, stream>>>((const float4*)in, (ushort4*)outp, n4);
    };
    cvt(x, xbf, XN);
    cvt(ipw, ipwbf, WIP);
    cvt(dtw, wcat, WSQ);
    cvt(bw, wcat + WSQ, WSQ);
    cvt(cwt, wcat + 2 * WSQ, WSQ);
    cvt(ow, owbf, WOUT);

    const int nchunks = SEQ / Lc;
    for (int c = 0; c < nchunks; ++c) {
        const int l0 = c * Lc;
        // 1. z=2: xb(S1) | sig(z)(S5) = epilogues of x @ ipw^T  (A fetched once)
        gemm256_ep<<<gXZ, blk512, 0, stream>>>(
            (const bf16_t*)xbf, (const bf16_t*)ipwbf, ipb,
            S1, S5, nullptr, nullptr,
            DMODEL, DINNER, Lc, SEQ, l0, Lc, 0, EP_XZ);
        // 2. u = silu(conv(xb))
        conv_silu_bf<<<pwBlocks, blk, 0, stream>>>(S1, tailb, cw, cb, S2, Lc, l0, NBe);
        if (nchunks > 1)
            tail_update_bf<<<BATCH * 3 * DINNER / 256, blk, 0, stream>>>(S1, tailb, Lc);
        // 3. z=3: decay(S3) | bt(S4) | ct(S1) from u @ [dtw;bw;cw]^T
        gemm256_ep<<<gDBC, blk512, 0, stream>>>(
            (const bf16_t*)S2, (const bf16_t*)wcat, dtb,
            S3, S4, S1, alog,
            DINNER, DINNER, Lc, Lc, 0, Lc, 0, EP_DBC);
        // 4-5. scan partials + combine (inc computed on the fly)
        scan1_v4<<<scanBlocks, blk, 0, stream>>>(S3, S4, S2, Pb, Sb, Lc, nsub);
        scan_p2<<<BATCH * DINNER / 256, blk, 0, stream>>>(Pb, Sb, carry, nsub, c == 0);
        // 6. replay + y = (ct*st + D*u)*sig -> gated ybf (in place over S4)
        p3y_v4<<<scanBlocks, blk, 0, stream>>>(S3, S4, S1, S2, S5, dpar, Pb, Lc, nsub);
        // 7. out = y @ ow^T + ob  (f32, 128^2: 512 blocks = 2/CU)
        gemm_f32out<<<gOut, blk, 0, stream>>>(
            (const bf16_t*)S4, (const bf16_t*)owbf, ob,
            out, DINNER, DMODEL, Lc, Lc, 0, SEQ, l0);
    }
}